// Round 5
// baseline (369.981 us; speedup 1.0000x reference)
//
#include <hip/hip_runtime.h>
#include <math.h>

#define B_   2
#define N_   2048
#define D_   1024
#define H_   16
#define HD_  64
#define BH_  32
#define M_   4096   // B_*N_

typedef __bf16 bf16x8 __attribute__((ext_vector_type(8)));
typedef float  f32x4  __attribute__((ext_vector_type(4)));
typedef __attribute__((address_space(3))) uint  lds_u32;
typedef __attribute__((address_space(1))) uint  glob_u32;

__device__ inline unsigned short f2b(float f) {
    unsigned u = __float_as_uint(f);
    u += 0x7FFFu + ((u >> 16) & 1u);
    return (unsigned short)(u >> 16);
}
// cheap round-to-nearest-ish bf16 (1 ulp vs RNE on ties; P has huge margin)
__device__ inline unsigned short f2b_fast(float f) {
    return (unsigned short)((__float_as_uint(f) + 0x8000u) >> 16);
}

// ---------------------------------------------------------------------------
// Convert x (4096x1024) and Wq/Wk/Wv/Wo (1024x1024 each) fp32 -> bf16 into one
// contiguous ws region: [x | wq | wk | wv | wo].
// ---------------------------------------------------------------------------
__global__ __launch_bounds__(256)
void cvt_all(const float* __restrict__ x,  const float* __restrict__ wq,
             const float* __restrict__ wk, const float* __restrict__ wv,
             const float* __restrict__ wo, ushort* __restrict__ dst)
{
    int i = blockIdx.x * 256 + threadIdx.x;      // float4 index
    if (i >= 2097152) return;                    // (4096*1024 + 4*1024*1024)/4
    int fi = i * 4;
    const float* s; int off;
    if (fi < 4194304) { s = x; off = fi; }
    else {
        int r = fi - 4194304;
        int wsel = r >> 20;                      // each W = 2^20 elements
        off = r & 1048575;
        s = (wsel == 0) ? wq : (wsel == 1) ? wk : (wsel == 2) ? wv : wo;
    }
    float4 f = *(const float4*)(s + off);
    ushort4 o;
    o.x = f2b(f.x); o.y = f2b(f.y); o.z = f2b(f.z); o.w = f2b(f.w);
    *(ushort4*)(dst + fi) = o;
}

// ---------------------------------------------------------------------------
// bf16 MFMA GEMM: C = A @ W^T. A [Mx1024] bf16 row-major, W [1024x1024] bf16
// row-major. 128x128 tile, 4 waves 2x2, 64x64/wave, BK=32.
// Staging via global_load_lds width=16 (m97 pattern): LDS unpadded [128][32].
// MODE 0: z selects Wq/Wk/Wv. z=0 (Q) scaled 0.125, scatter [BH][N][64];
//         z=1 (K) scatter [BH][N][64]; z=2 (V) written TRANSPOSED [BH][HD][N].
// MODE 1: fp32 [Mx1024] + bias.
// ---------------------------------------------------------------------------
template <int MODE>
__global__ __launch_bounds__(256)
void gemm_mfma(const ushort* __restrict__ A,
               const ushort* __restrict__ W0, const ushort* __restrict__ W1,
               const ushort* __restrict__ W2, const float* __restrict__ bias,
               ushort* __restrict__ O0, ushort* __restrict__ O1,
               ushort* __restrict__ O2, float* __restrict__ Of)
{
    const int z = blockIdx.z;
    const ushort* W = (z == 0) ? W0 : (z == 1) ? W1 : W2;

    __shared__ alignas(16) ushort As[128][32];
    __shared__ alignas(16) ushort Bs[128][32];

    const int t = threadIdx.x;
    const int lane = t & 63, w = t >> 6;
    const int quad = lane >> 4, l15 = lane & 15;
    const int wm = (w >> 1) * 64, wn = (w & 1) * 64;
    const int tileM = blockIdx.x * 128, tileN = blockIdx.y * 128;
    const int crow = lane >> 2;          // chunk row 0..15
    const int ccol = (lane & 3) * 8;     // ushort col offset

    f32x4 acc[4][4];
#pragma unroll
    for (int mt = 0; mt < 4; ++mt)
#pragma unroll
        for (int nt = 0; nt < 4; ++nt) acc[mt][nt] = (f32x4){0.f, 0.f, 0.f, 0.f};

    for (int k0 = 0; k0 < D_; k0 += 32) {
        __syncthreads();
#pragma unroll
        for (int cc = 0; cc < 2; ++cc) {
            int ch = w * 2 + cc;
            const ushort* ga = &A[(size_t)(tileM + ch * 16 + crow) * D_ + k0 + ccol];
            __builtin_amdgcn_global_load_lds((const glob_u32*)ga, (lds_u32*)&As[ch * 16][0], 16, 0, 0);
            const ushort* gb = &W[(size_t)(tileN + ch * 16 + crow) * D_ + k0 + ccol];
            __builtin_amdgcn_global_load_lds((const glob_u32*)gb, (lds_u32*)&Bs[ch * 16][0], 16, 0, 0);
        }
        __syncthreads();

        bf16x8 af[4], bf[4];
#pragma unroll
        for (int mt = 0; mt < 4; ++mt) af[mt] = *(const bf16x8*)&As[wm + mt * 16 + l15][quad * 8];
#pragma unroll
        for (int nt = 0; nt < 4; ++nt) bf[nt] = *(const bf16x8*)&Bs[wn + nt * 16 + l15][quad * 8];
#pragma unroll
        for (int mt = 0; mt < 4; ++mt)
#pragma unroll
            for (int nt = 0; nt < 4; ++nt)
                acc[mt][nt] = __builtin_amdgcn_mfma_f32_16x16x32_bf16(af[mt], bf[nt], acc[mt][nt], 0, 0, 0);
    }

    ushort* O = (z == 0) ? O0 : (z == 1) ? O1 : O2;
    const float scl = (MODE == 0 && z == 0) ? 0.125f : 1.0f;
#pragma unroll
    for (int mt = 0; mt < 4; ++mt)
#pragma unroll
        for (int nt = 0; nt < 4; ++nt) {
            if (MODE == 0 && z == 2) {
                int rg0 = tileM + wm + mt * 16 + quad * 4;
                int cg  = tileN + wn + nt * 16 + l15;
                int b = rg0 >> 11, n0 = rg0 & (N_ - 1);
                int h = cg >> 6, dd = cg & 63;
                ushort4 o4;
                o4.x = f2b(acc[mt][nt][0]); o4.y = f2b(acc[mt][nt][1]);
                o4.z = f2b(acc[mt][nt][2]); o4.w = f2b(acc[mt][nt][3]);
                *(ushort4*)&O[((size_t)((b * H_ + h) * HD_ + dd)) * N_ + n0] = o4;
            } else {
#pragma unroll
                for (int r = 0; r < 4; ++r) {
                    int rg = tileM + wm + mt * 16 + quad * 4 + r;
                    int cg = tileN + wn + nt * 16 + l15;
                    float v = acc[mt][nt][r];
                    if (MODE == 0) {
                        int b = rg >> 11, n = rg & (N_ - 1);
                        int h = cg >> 6, dd = cg & 63;
                        O[(((size_t)(b * H_ + h)) * N_ + n) * HD_ + dd] = f2b(v * scl);
                    } else {
                        Of[(size_t)rg * D_ + cg] = v + bias[cg];
                    }
                }
            }
        }
}

// ---------------------------------------------------------------------------
// Barrier-free MFMA adaptive-temperature causal flash attention.
// 1D grid 1024 blocks, LPT order (qt descending), bh = bid&31 (XCD locality).
// 4 waves/block; wave w owns queries qt*64 + w*16 .. +15; NO __syncthreads.
// K [BH][N][64] and VT [BH][64][N] are L2-resident (512 KB per bh); MFMA
// B-fragments are 16B/lane CONTIGUOUS in both, so frags load directly
// global->VGPR (global_load_dwordx4) -- no K/V LDS staging, no barriers.
// LDS holds only the wave-private P roundtrip (C-layout write -> A-layout
// read, same-wave, compiler-inserted lgkmcnt).
//   QK^T B-frag (k=d=quad*8+j, n=key=l15):  K[kb*64+nt*16+l15][quad*8+..]
//   PV   B-frag (k=key=quad*8+j, n=hd=l15): VT[nt*16+l15][kb*64+quad*8+..]
// Fixed shift C=8 (entropy/beta-softmax shift-invariant, |s|<~8).
// Pass 1: Z=sum e^(s-C), S=sum (s-C)e^(s-C) -> H=logZ-S/Z -> beta.
// Pass 2: w=e^(beta*(s-C)); O += w*V, Z' += w; final O/Z'.
// Shuffle reductions hoisted out of the kb loops (linear -> reduce once).
// Diagonal key-block specialized (mask VALU only there).
// ---------------------------------------------------------------------------
__global__ __launch_bounds__(256)
void attn_mfma(const ushort* __restrict__ Q, const ushort* __restrict__ K,
               const ushort* __restrict__ VT, ushort* __restrict__ AO)
{
    const int bid = blockIdx.x;
    const int qt = 31 - (bid >> 5);
    const int bh = bid & 31;
    const size_t kvbase = (size_t)bh * N_ * HD_;

    __shared__ alignas(16) ushort Ps[4][16][72];    // wave-private P (9.2 KB)

    const int t = threadIdx.x;
    const int lane = t & 63, w = t >> 6;
    const int quad = lane >> 4, l15 = lane & 15;
    const float SH = 8.0f;

    // lane-fixed global fragment bases
    const ushort* Kl = K  + kvbase + (size_t)l15 * HD_ + quad * 8;   // + kb*4096 + nt*1024 (+32)
    const ushort* Vl = VT + kvbase + (size_t)l15 * N_  + quad * 8;   // + nt*16*N_ + kb*64 (+32)

    // Q fragments (registers all kernel)
    bf16x8 aq0, aq1;
    {
        const size_t qr = kvbase + (size_t)(qt * 64 + w * 16 + l15) * HD_;
        aq0 = *(const bf16x8*)&Q[qr + quad * 8];
        aq1 = *(const bf16x8*)&Q[qr + 32 + quad * 8];
    }

    float ez[4] = {0.f, 0.f, 0.f, 0.f};
    float sz[4] = {0.f, 0.f, 0.f, 0.f};

    // ---------------- pass 1: Z, S (off-diagonal: no masks) ----------------
    for (int kb = 0; kb < qt; ++kb) {
        const ushort* kp = Kl + kb * (64 * HD_);
#pragma unroll
        for (int nt = 0; nt < 4; ++nt) {
            f32x4 sv = (f32x4){0.f, 0.f, 0.f, 0.f};
            sv = __builtin_amdgcn_mfma_f32_16x16x32_bf16(aq0, *(const bf16x8*)(kp + nt * (16 * HD_)), sv, 0, 0, 0);
            sv = __builtin_amdgcn_mfma_f32_16x16x32_bf16(aq1, *(const bf16x8*)(kp + nt * (16 * HD_) + 32), sv, 0, 0, 0);
#pragma unroll
            for (int r = 0; r < 4; ++r) {
                float sh = sv[r] - SH;
                float e = __expf(sh);
                ez[r] += e;
                sz[r] = fmaf(e, sh, sz[r]);
            }
        }
    }
    {   // diagonal block (kb == qt): causal mask
        const ushort* kp = Kl + qt * (64 * HD_);
        const int qrow = w * 16 + quad * 4;
#pragma unroll
        for (int nt = 0; nt < 4; ++nt) {
            f32x4 sv = (f32x4){0.f, 0.f, 0.f, 0.f};
            sv = __builtin_amdgcn_mfma_f32_16x16x32_bf16(aq0, *(const bf16x8*)(kp + nt * (16 * HD_)), sv, 0, 0, 0);
            sv = __builtin_amdgcn_mfma_f32_16x16x32_bf16(aq1, *(const bf16x8*)(kp + nt * (16 * HD_) + 32), sv, 0, 0, 0);
            const int kcol = nt * 16 + l15;
#pragma unroll
            for (int r = 0; r < 4; ++r) {
                float sh = sv[r] - SH;
                float e = (kcol <= qrow + r) ? __expf(sh) : 0.f;
                ez[r] += e;
                sz[r] = fmaf(e, sh, sz[r]);
            }
        }
    }
    // one butterfly reduce over the 16-lane group (hoisted out of kb loop)
#pragma unroll
    for (int r = 0; r < 4; ++r) {
#pragma unroll
        for (int off = 1; off < 16; off <<= 1) {
            ez[r] += __shfl_xor(ez[r], off);
            sz[r] += __shfl_xor(sz[r], off);
        }
    }

    // ---------------- entropy -> beta ----------------
    float nbs[4], bl[4];   // w = exp(beta*(s-SH)) = exp(fma(beta, s, -beta*SH))
#pragma unroll
    for (int r = 0; r < 4; ++r) {
        float Z = ez[r];
        float Hh = __logf(Z) - sz[r] / Z;
        float bb = 1.f;
        if (Hh > 0.5f) {
            float e2 = Hh * Hh;
            float p = -0.037f * e2 * e2 + 0.481f * e2 * Hh - 2.3f * e2 + 4.917f * Hh - 1.791f;
            bb = fmaxf(p, 1.f);
        }
        bl[r] = bb;
        nbs[r] = -bb * SH;
    }

    // ---------------- pass 2: O, Z' ----------------
    f32x4 ov[4];
#pragma unroll
    for (int nt = 0; nt < 4; ++nt) ov[nt] = (f32x4){0.f, 0.f, 0.f, 0.f};
    float zp[4] = {0.f, 0.f, 0.f, 0.f};

    for (int kb = 0; kb <= qt; ++kb) {
        const ushort* kp = Kl + kb * (64 * HD_);
        const bool diag = (kb == qt);
        const int qrow = w * 16 + quad * 4;

        float wv[4][4];
#pragma unroll
        for (int nt = 0; nt < 4; ++nt) {
            f32x4 sv = (f32x4){0.f, 0.f, 0.f, 0.f};
            sv = __builtin_amdgcn_mfma_f32_16x16x32_bf16(aq0, *(const bf16x8*)(kp + nt * (16 * HD_)), sv, 0, 0, 0);
            sv = __builtin_amdgcn_mfma_f32_16x16x32_bf16(aq1, *(const bf16x8*)(kp + nt * (16 * HD_) + 32), sv, 0, 0, 0);
            const int kcol = nt * 16 + l15;
#pragma unroll
            for (int r = 0; r < 4; ++r) {
                float e = __expf(fmaf(bl[r], sv[r], nbs[r]));
                wv[nt][r] = (!diag || (kcol <= qrow + r)) ? e : 0.f;
            }
        }
        // P -> wave-private LDS (C-layout write, A-layout read; same-wave DS in-order)
#pragma unroll
        for (int nt = 0; nt < 4; ++nt)
#pragma unroll
            for (int r = 0; r < 4; ++r)
                Ps[w][quad * 4 + r][nt * 16 + l15] = f2b_fast(wv[nt][r]);
#pragma unroll
        for (int r = 0; r < 4; ++r)
            zp[r] += (wv[0][r] + wv[1][r]) + (wv[2][r] + wv[3][r]);

        bf16x8 pa0 = *(const bf16x8*)&Ps[w][l15][quad * 8];
        bf16x8 pa1 = *(const bf16x8*)&Ps[w][l15][32 + quad * 8];
        const ushort* vp = Vl + kb * 64;
#pragma unroll
        for (int nt = 0; nt < 4; ++nt) {
            ov[nt] = __builtin_amdgcn_mfma_f32_16x16x32_bf16(pa0, *(const bf16x8*)(vp + (size_t)nt * 16 * N_), ov[nt], 0, 0, 0);
            ov[nt] = __builtin_amdgcn_mfma_f32_16x16x32_bf16(pa1, *(const bf16x8*)(vp + (size_t)nt * 16 * N_ + 32), ov[nt], 0, 0, 0);
        }
    }
    // hoisted Z' butterfly
#pragma unroll
    for (int r = 0; r < 4; ++r)
#pragma unroll
        for (int off = 1; off < 16; off <<= 1) zp[r] += __shfl_xor(zp[r], off);

    // ---------------- write AO [B, N, D] bf16 ----------------
    const int b = bh >> 4, h = bh & 15;
#pragma unroll
    for (int r = 0; r < 4; ++r) {
        int qg = qt * 64 + w * 16 + quad * 4 + r;
        float inv = 1.f / zp[r];
        size_t rowoff = ((size_t)(b * N_ + qg)) * D_ + h * HD_;
#pragma unroll
        for (int nt = 0; nt < 4; ++nt)
            AO[rowoff + nt * 16 + l15] = f2b(ov[nt][r] * inv);
    }
}

// ---------------------------------------------------------------------------
extern "C" void kernel_launch(void* const* d_in, const int* in_sizes, int n_in,
                              void* d_out, int out_size, void* d_ws, size_t ws_size,
                              hipStream_t stream)
{
    const float* x  = (const float*)d_in[0];
    const float* Wq = (const float*)d_in[1];
    const float* Wk = (const float*)d_in[2];
    const float* Wv = (const float*)d_in[3];
    const float* Wo = (const float*)d_in[4];
    const float* bo = (const float*)d_in[5];
    float* out = (float*)d_out;

    ushort* ws  = (ushort*)d_ws;
    ushort* xb  = ws;                       // 4096*1024
    ushort* wqb = ws + 4194304;
    ushort* wkb = ws + 5242880;
    ushort* wvb = ws + 6291456;
    ushort* wob = ws + 7340032;
    ushort* Qb  = ws + 8388608;             // [32][2048][64]
    ushort* Kb  = ws + 12582912;            // [32][2048][64]
    ushort* Vtb = ws + 16777216;            // [32][64][2048]  (transposed V)
    ushort* aob = ws + 20971520;            // 4096*1024

    cvt_all<<<8192, 256, 0, stream>>>(x, Wq, Wk, Wv, Wo, xb);

    gemm_mfma<0><<<dim3(32, 8, 3), 256, 0, stream>>>(
        xb, wqb, wkb, wvb, nullptr, Qb, Kb, Vtb, nullptr);

    attn_mfma<<<dim3(1024), 256, 0, stream>>>(Qb, Kb, Vtb, aob);

    gemm_mfma<1><<<dim3(32, 8, 1), 256, 0, stream>>>(
        aob, wob, nullptr, nullptr, bo, nullptr, nullptr, nullptr, out);
}

// Round 6
// 216.979 us; speedup vs baseline: 1.7051x; 1.7051x over previous
//
#include <hip/hip_runtime.h>
#include <math.h>

#define B_   2
#define N_   2048
#define D_   1024
#define H_   16
#define HD_  64
#define BH_  32
#define M_   4096   // B_*N_

typedef __bf16 bf16x8 __attribute__((ext_vector_type(8)));
typedef float  f32x4  __attribute__((ext_vector_type(4)));
typedef __attribute__((address_space(3))) uint  lds_u32;
typedef __attribute__((address_space(1))) uint  glob_u32;

__device__ inline unsigned short f2b(float f) {
    unsigned u = __float_as_uint(f);
    u += 0x7FFFu + ((u >> 16) & 1u);
    return (unsigned short)(u >> 16);
}
// cheap round (1 ulp vs RNE on ties; P has huge margin)
__device__ inline unsigned short f2b_fast(float f) {
    return (unsigned short)((__float_as_uint(f) + 0x8000u) >> 16);
}

// ---------------------------------------------------------------------------
// Convert x (4096x1024) and Wq/Wk/Wv/Wo (1024x1024 each) fp32 -> bf16 into one
// contiguous ws region: [x | wq | wk | wv | wo].
// ---------------------------------------------------------------------------
__global__ __launch_bounds__(256)
void cvt_all(const float* __restrict__ x,  const float* __restrict__ wq,
             const float* __restrict__ wk, const float* __restrict__ wv,
             const float* __restrict__ wo, ushort* __restrict__ dst)
{
    int i = blockIdx.x * 256 + threadIdx.x;      // float4 index
    if (i >= 2097152) return;                    // (4096*1024 + 4*1024*1024)/4
    int fi = i * 4;
    const float* s; int off;
    if (fi < 4194304) { s = x; off = fi; }
    else {
        int r = fi - 4194304;
        int wsel = r >> 20;                      // each W = 2^20 elements
        off = r & 1048575;
        s = (wsel == 0) ? wq : (wsel == 1) ? wk : (wsel == 2) ? wv : wo;
    }
    float4 f = *(const float4*)(s + off);
    ushort4 o;
    o.x = f2b(f.x); o.y = f2b(f.y); o.z = f2b(f.z); o.w = f2b(f.w);
    *(ushort4*)(dst + fi) = o;
}

// ---------------------------------------------------------------------------
// bf16 MFMA GEMM: C = A @ W^T. A [Mx1024] bf16 row-major, W [1024x1024] bf16
// row-major. 128x128 tile, 4 waves 2x2, 64x64/wave, BK=32.
// Staging via global_load_lds width=16 (m97 pattern): LDS unpadded [128][32].
// MODE 0: z selects Wq/Wk/Wv. z=0 (Q) scaled 0.125, scatter [BH][N][64];
//         z=1 (K) scatter [BH][N][64]; z=2 (V) written TRANSPOSED [BH][HD][N].
// MODE 1: fp32 [Mx1024] + bias.
// ---------------------------------------------------------------------------
template <int MODE>
__global__ __launch_bounds__(256)
void gemm_mfma(const ushort* __restrict__ A,
               const ushort* __restrict__ W0, const ushort* __restrict__ W1,
               const ushort* __restrict__ W2, const float* __restrict__ bias,
               ushort* __restrict__ O0, ushort* __restrict__ O1,
               ushort* __restrict__ O2, float* __restrict__ Of)
{
    const int z = blockIdx.z;
    const ushort* W = (z == 0) ? W0 : (z == 1) ? W1 : W2;

    __shared__ alignas(16) ushort As[128][32];
    __shared__ alignas(16) ushort Bs[128][32];

    const int t = threadIdx.x;
    const int lane = t & 63, w = t >> 6;
    const int quad = lane >> 4, l15 = lane & 15;
    const int wm = (w >> 1) * 64, wn = (w & 1) * 64;
    const int tileM = blockIdx.x * 128, tileN = blockIdx.y * 128;
    const int crow = lane >> 2;          // chunk row 0..15
    const int ccol = (lane & 3) * 8;     // ushort col offset

    f32x4 acc[4][4];
#pragma unroll
    for (int mt = 0; mt < 4; ++mt)
#pragma unroll
        for (int nt = 0; nt < 4; ++nt) acc[mt][nt] = (f32x4){0.f, 0.f, 0.f, 0.f};

    for (int k0 = 0; k0 < D_; k0 += 32) {
        __syncthreads();
#pragma unroll
        for (int cc = 0; cc < 2; ++cc) {
            int ch = w * 2 + cc;
            const ushort* ga = &A[(size_t)(tileM + ch * 16 + crow) * D_ + k0 + ccol];
            __builtin_amdgcn_global_load_lds((const glob_u32*)ga, (lds_u32*)&As[ch * 16][0], 16, 0, 0);
            const ushort* gb = &W[(size_t)(tileN + ch * 16 + crow) * D_ + k0 + ccol];
            __builtin_amdgcn_global_load_lds((const glob_u32*)gb, (lds_u32*)&Bs[ch * 16][0], 16, 0, 0);
        }
        __syncthreads();

        bf16x8 af[4], bf[4];
#pragma unroll
        for (int mt = 0; mt < 4; ++mt) af[mt] = *(const bf16x8*)&As[wm + mt * 16 + l15][quad * 8];
#pragma unroll
        for (int nt = 0; nt < 4; ++nt) bf[nt] = *(const bf16x8*)&Bs[wn + nt * 16 + l15][quad * 8];
#pragma unroll
        for (int mt = 0; mt < 4; ++mt)
#pragma unroll
            for (int nt = 0; nt < 4; ++nt)
                acc[mt][nt] = __builtin_amdgcn_mfma_f32_16x16x32_bf16(af[mt], bf[nt], acc[mt][nt], 0, 0, 0);
    }

    ushort* O = (z == 0) ? O0 : (z == 1) ? O1 : O2;
    const float scl = (MODE == 0 && z == 0) ? 0.125f : 1.0f;
#pragma unroll
    for (int mt = 0; mt < 4; ++mt)
#pragma unroll
        for (int nt = 0; nt < 4; ++nt) {
            if (MODE == 0 && z == 2) {
                int rg0 = tileM + wm + mt * 16 + quad * 4;
                int cg  = tileN + wn + nt * 16 + l15;
                int b = rg0 >> 11, n0 = rg0 & (N_ - 1);
                int h = cg >> 6, dd = cg & 63;
                ushort4 o4;
                o4.x = f2b(acc[mt][nt][0]); o4.y = f2b(acc[mt][nt][1]);
                o4.z = f2b(acc[mt][nt][2]); o4.w = f2b(acc[mt][nt][3]);
                *(ushort4*)&O[((size_t)((b * H_ + h) * HD_ + dd)) * N_ + n0] = o4;
            } else {
#pragma unroll
                for (int r = 0; r < 4; ++r) {
                    int rg = tileM + wm + mt * 16 + quad * 4 + r;
                    int cg = tileN + wn + nt * 16 + l15;
                    float v = acc[mt][nt][r];
                    if (MODE == 0) {
                        int b = rg >> 11, n = rg & (N_ - 1);
                        int h = cg >> 6, dd = cg & 63;
                        O[(((size_t)(b * H_ + h)) * N_ + n) * HD_ + dd] = f2b(v * scl);
                    } else {
                        Of[(size_t)rg * D_ + cg] = v + bias[cg];
                    }
                }
            }
        }
}

// ---------------------------------------------------------------------------
// MFMA adaptive-temperature causal flash attention (LDS-staged, reg-prefetch).
// 1D grid 1024 blocks, LPT order (qt descending), bh = bid&31 (XCD locality).
// 4 waves; wave w owns queries qt*64 + w*16 .. +15.
// Q/K bf16 [BH][N][64]; V pre-transposed [BH][64][N]; Q pre-scaled 1/8.
// R5 lesson: per-fragment global(L2) loads put ~200-400cyc latency on every
// MFMA (113->225us). Staging via LDS (ds_read_b128 ~12cyc) is the latency
// amortizer. Here the staging GLOBAL loads for kb+1 are prefetched into VGPRs
// during kb's compute, so the vmcnt wait lands after a full tile of compute
// instead of draining at the barrier.
// Ps layout [wave][grp][r*72+col] (+8 pad per 4-row group): spreads the
// scalar u16 P-writes over ~28 banks (was 16 + sub-word collisions); b128
// A-frag reads stay 16B-aligned at the 8-words/bank minimum.
// Fixed shift C=8 (entropy/beta-softmax shift-invariant; |s|<~8).
// Pass 1: Z=sum e^(s-C), S=sum (s-C)e^(s-C) -> H=logZ-S/Z -> beta.
// Pass 2: w=e^(beta*(s-C)); O += w*V (P via wave-private LDS), Z'+=w; O/Z'.
// ---------------------------------------------------------------------------
__global__ __launch_bounds__(256)
void attn_mfma(const ushort* __restrict__ Q, const ushort* __restrict__ K,
               const ushort* __restrict__ VT, ushort* __restrict__ AO)
{
    const int bid = blockIdx.x;
    const int qt = 31 - (bid >> 5);
    const int bh = bid & 31;
    const size_t kvbase = (size_t)bh * N_ * HD_;

    __shared__ alignas(16) ushort Ks[64][72];       // [key][hd]
    __shared__ alignas(16) ushort Vt[64][72];       // [hd][key]
    __shared__ alignas(16) ushort Ps[4][4][296];    // wave-private P, grp-padded

    const int t = threadIdx.x;
    const int lane = t & 63, w = t >> 6;
    const int quad = lane >> 4, l15 = lane & 15;
    const float SH = 8.0f;

    // staging: thread t covers chunks (skey, skc) and (32+skey, skc)
    const int skey = t >> 3;            // 0..31
    const int skc  = (t & 7) * 8;       // 0..56
    const ushort* KS0 = K  + kvbase + (size_t)skey * HD_ + skc;        // + kb*64*HD_
    const ushort* KS1 = KS0 + 32 * HD_;
    const ushort* VS0 = VT + kvbase + (size_t)skey * N_ + skc;         // + kb*64
    const ushort* VS1 = VS0 + 32 * N_;

    // Q fragments (registers all kernel)
    bf16x8 aq0, aq1;
    {
        const size_t qr = kvbase + (size_t)(qt * 64 + w * 16 + l15) * HD_;
        aq0 = *(const bf16x8*)&Q[qr + quad * 8];
        aq1 = *(const bf16x8*)&Q[qr + 32 + quad * 8];
    }
    const int qrow = w * 16 + quad * 4;

    float ez[4] = {0.f, 0.f, 0.f, 0.f};
    float sz[4] = {0.f, 0.f, 0.f, 0.f};

    // ---------------- pass 1: Z, S ----------------
    uint4 pk0 = *(const uint4*)KS0;
    uint4 pk1 = *(const uint4*)KS1;
    for (int kb = 0; kb <= qt; ++kb) {
        __syncthreads();                       // prev tile's readers done
        *(uint4*)&Ks[skey][skc]      = pk0;    // vmcnt wait here, hidden by prev compute
        *(uint4*)&Ks[32 + skey][skc] = pk1;
        __syncthreads();
        if (kb < qt) {                         // prefetch kb+1 (consumed next iter)
            pk0 = *(const uint4*)(KS0 + (size_t)(kb + 1) * (64 * HD_));
            pk1 = *(const uint4*)(KS1 + (size_t)(kb + 1) * (64 * HD_));
        }
        if (kb < qt) {                         // off-diagonal: no masks
#pragma unroll
            for (int nt = 0; nt < 4; ++nt) {
                f32x4 sv = (f32x4){0.f, 0.f, 0.f, 0.f};
                sv = __builtin_amdgcn_mfma_f32_16x16x32_bf16(aq0, *(const bf16x8*)&Ks[nt * 16 + l15][quad * 8], sv, 0, 0, 0);
                sv = __builtin_amdgcn_mfma_f32_16x16x32_bf16(aq1, *(const bf16x8*)&Ks[nt * 16 + l15][32 + quad * 8], sv, 0, 0, 0);
#pragma unroll
                for (int r = 0; r < 4; ++r) {
                    float sh = sv[r] - SH;
                    float e = __expf(sh);
                    ez[r] += e;
                    sz[r] = fmaf(e, sh, sz[r]);
                }
            }
        } else {                               // diagonal: causal mask
#pragma unroll
            for (int nt = 0; nt < 4; ++nt) {
                f32x4 sv = (f32x4){0.f, 0.f, 0.f, 0.f};
                sv = __builtin_amdgcn_mfma_f32_16x16x32_bf16(aq0, *(const bf16x8*)&Ks[nt * 16 + l15][quad * 8], sv, 0, 0, 0);
                sv = __builtin_amdgcn_mfma_f32_16x16x32_bf16(aq1, *(const bf16x8*)&Ks[nt * 16 + l15][32 + quad * 8], sv, 0, 0, 0);
                const int kcol = nt * 16 + l15;
#pragma unroll
                for (int r = 0; r < 4; ++r) {
                    float sh = sv[r] - SH;
                    float e = (kcol <= qrow + r) ? __expf(sh) : 0.f;
                    ez[r] += e;
                    sz[r] = fmaf(e, sh, sz[r]);
                }
            }
        }
    }
    // hoisted 16-lane butterfly reduce
#pragma unroll
    for (int r = 0; r < 4; ++r) {
#pragma unroll
        for (int off = 1; off < 16; off <<= 1) {
            ez[r] += __shfl_xor(ez[r], off);
            sz[r] += __shfl_xor(sz[r], off);
        }
    }

    // ---------------- entropy -> beta ----------------
    float nbs[4], bl[4];   // w = exp(fma(beta, s, -beta*SH))
#pragma unroll
    for (int r = 0; r < 4; ++r) {
        float Z = ez[r];
        float Hh = __logf(Z) - sz[r] / Z;
        float bb = 1.f;
        if (Hh > 0.5f) {
            float e2 = Hh * Hh;
            float p = -0.037f * e2 * e2 + 0.481f * e2 * Hh - 2.3f * e2 + 4.917f * Hh - 1.791f;
            bb = fmaxf(p, 1.f);
        }
        bl[r] = bb;
        nbs[r] = -bb * SH;
    }

    // ---------------- pass 2: O, Z' ----------------
    f32x4 ov[4];
#pragma unroll
    for (int nt = 0; nt < 4; ++nt) ov[nt] = (f32x4){0.f, 0.f, 0.f, 0.f};
    float zp[4] = {0.f, 0.f, 0.f, 0.f};

    pk0 = *(const uint4*)KS0;
    pk1 = *(const uint4*)KS1;
    uint4 pv0 = *(const uint4*)VS0;
    uint4 pv1 = *(const uint4*)VS1;
    for (int kb = 0; kb <= qt; ++kb) {
        __syncthreads();
        *(uint4*)&Ks[skey][skc]      = pk0;
        *(uint4*)&Ks[32 + skey][skc] = pk1;
        *(uint4*)&Vt[skey][skc]      = pv0;
        *(uint4*)&Vt[32 + skey][skc] = pv1;
        __syncthreads();
        if (kb < qt) {
            pk0 = *(const uint4*)(KS0 + (size_t)(kb + 1) * (64 * HD_));
            pk1 = *(const uint4*)(KS1 + (size_t)(kb + 1) * (64 * HD_));
            pv0 = *(const uint4*)(VS0 + (kb + 1) * 64);
            pv1 = *(const uint4*)(VS1 + (kb + 1) * 64);
        }
        const bool diag = (kb == qt);

        float wv[4][4];
#pragma unroll
        for (int nt = 0; nt < 4; ++nt) {
            f32x4 sv = (f32x4){0.f, 0.f, 0.f, 0.f};
            sv = __builtin_amdgcn_mfma_f32_16x16x32_bf16(aq0, *(const bf16x8*)&Ks[nt * 16 + l15][quad * 8], sv, 0, 0, 0);
            sv = __builtin_amdgcn_mfma_f32_16x16x32_bf16(aq1, *(const bf16x8*)&Ks[nt * 16 + l15][32 + quad * 8], sv, 0, 0, 0);
            const int kcol = nt * 16 + l15;
#pragma unroll
            for (int r = 0; r < 4; ++r) {
                float e = __expf(fmaf(bl[r], sv[r], nbs[r]));
                wv[nt][r] = (!diag || (kcol <= qrow + r)) ? e : 0.f;
            }
        }
        // P -> wave-private LDS (C-layout write, A-layout read; same-wave DS in-order)
#pragma unroll
        for (int nt = 0; nt < 4; ++nt)
#pragma unroll
            for (int r = 0; r < 4; ++r)
                Ps[w][quad][r * 72 + nt * 16 + l15] = f2b_fast(wv[nt][r]);
#pragma unroll
        for (int r = 0; r < 4; ++r)
            zp[r] += (wv[0][r] + wv[1][r]) + (wv[2][r] + wv[3][r]);

        bf16x8 pa0 = *(const bf16x8*)&Ps[w][l15 >> 2][(l15 & 3) * 72 + quad * 8];
        bf16x8 pa1 = *(const bf16x8*)&Ps[w][l15 >> 2][(l15 & 3) * 72 + 32 + quad * 8];
#pragma unroll
        for (int nt = 0; nt < 4; ++nt) {
            ov[nt] = __builtin_amdgcn_mfma_f32_16x16x32_bf16(pa0, *(const bf16x8*)&Vt[nt * 16 + l15][quad * 8], ov[nt], 0, 0, 0);
            ov[nt] = __builtin_amdgcn_mfma_f32_16x16x32_bf16(pa1, *(const bf16x8*)&Vt[nt * 16 + l15][32 + quad * 8], ov[nt], 0, 0, 0);
        }
    }
    // hoisted Z' butterfly
#pragma unroll
    for (int r = 0; r < 4; ++r)
#pragma unroll
        for (int off = 1; off < 16; off <<= 1) zp[r] += __shfl_xor(zp[r], off);

    // ---------------- write AO [B, N, D] bf16 ----------------
    const int b = bh >> 4, h = bh & 15;
#pragma unroll
    for (int r = 0; r < 4; ++r) {
        int qg = qt * 64 + w * 16 + quad * 4 + r;
        float inv = 1.f / zp[r];
        size_t rowoff = ((size_t)(b * N_ + qg)) * D_ + h * HD_;
#pragma unroll
        for (int nt = 0; nt < 4; ++nt)
            AO[rowoff + nt * 16 + l15] = f2b(ov[nt][r] * inv);
    }
}

// ---------------------------------------------------------------------------
extern "C" void kernel_launch(void* const* d_in, const int* in_sizes, int n_in,
                              void* d_out, int out_size, void* d_ws, size_t ws_size,
                              hipStream_t stream)
{
    const float* x  = (const float*)d_in[0];
    const float* Wq = (const float*)d_in[1];
    const float* Wk = (const float*)d_in[2];
    const float* Wv = (const float*)d_in[3];
    const float* Wo = (const float*)d_in[4];
    const float* bo = (const float*)d_in[5];
    float* out = (float*)d_out;

    ushort* ws  = (ushort*)d_ws;
    ushort* xb  = ws;                       // 4096*1024
    ushort* wqb = ws + 4194304;
    ushort* wkb = ws + 5242880;
    ushort* wvb = ws + 6291456;
    ushort* wob = ws + 7340032;
    ushort* Qb  = ws + 8388608;             // [32][2048][64]
    ushort* Kb  = ws + 12582912;            // [32][2048][64]
    ushort* Vtb = ws + 16777216;            // [32][64][2048]  (transposed V)
    ushort* aob = ws + 20971520;            // 4096*1024

    cvt_all<<<8192, 256, 0, stream>>>(x, Wq, Wk, Wv, Wo, xb);

    gemm_mfma<0><<<dim3(32, 8, 3), 256, 0, stream>>>(
        xb, wqb, wkb, wvb, nullptr, Qb, Kb, Vtb, nullptr);

    attn_mfma<<<dim3(1024), 256, 0, stream>>>(Qb, Kb, Vtb, aob);

    gemm_mfma<1><<<dim3(32, 8, 1), 256, 0, stream>>>(
        aob, wob, nullptr, nullptr, bo, nullptr, nullptr, nullptr, out);
}

// Round 7
// 205.829 us; speedup vs baseline: 1.7975x; 1.0542x over previous
//
#include <hip/hip_runtime.h>
#include <math.h>

#define B_   2
#define N_   2048
#define D_   1024
#define H_   16
#define HD_  64
#define BH_  32
#define M_   4096   // B_*N_

typedef __bf16 bf16x8 __attribute__((ext_vector_type(8)));
typedef float  f32x4  __attribute__((ext_vector_type(4)));

__device__ inline unsigned short f2b(float f) {
    unsigned u = __float_as_uint(f);
    u += 0x7FFFu + ((u >> 16) & 1u);
    return (unsigned short)(u >> 16);
}
// cheap round (1 ulp vs RNE on ties; P has huge margin)
__device__ inline unsigned short f2b_fast(float f) {
    return (unsigned short)((__float_as_uint(f) + 0x8000u) >> 16);
}

// ---------------------------------------------------------------------------
// Convert x (4096x1024) and Wq/Wk/Wv/Wo (1024x1024 each) fp32 -> bf16 into one
// contiguous ws region: [x | wq | wk | wv | wo].
// ---------------------------------------------------------------------------
__global__ __launch_bounds__(256)
void cvt_all(const float* __restrict__ x,  const float* __restrict__ wq,
             const float* __restrict__ wk, const float* __restrict__ wv,
             const float* __restrict__ wo, ushort* __restrict__ dst)
{
    int i = blockIdx.x * 256 + threadIdx.x;      // float4 index
    if (i >= 2097152) return;                    // (4096*1024 + 4*1024*1024)/4
    int fi = i * 4;
    const float* s; int off;
    if (fi < 4194304) { s = x; off = fi; }
    else {
        int r = fi - 4194304;
        int wsel = r >> 20;                      // each W = 2^20 elements
        off = r & 1048575;
        s = (wsel == 0) ? wq : (wsel == 1) ? wk : (wsel == 2) ? wv : wo;
    }
    float4 f = *(const float4*)(s + off);
    ushort4 o;
    o.x = f2b(f.x); o.y = f2b(f.y); o.z = f2b(f.z); o.w = f2b(f.w);
    *(ushort4*)(dst + fi) = o;
}

// ---------------------------------------------------------------------------
// QKV bf16 MFMA GEMM: C = A @ W^T. A [Mx1024], W [1024x1024], both row-major.
// 128x128 tile, 4 waves 2x2, 64x64/wave, BK=32.
// R7: register-prefetch staging (R6 attn pattern): kb+1's A/B tiles load into
// VGPRs right after the barrier, consumed next iteration -> the vmcnt wait
// sits behind a full tile of MFMA instead of draining at the barrier.
// (R3/R4 data: global_load_lds staging was ~neutral-to-worse here; its
// vmcnt(0)+barrier drain stalls all waves at 3 blocks/CU.)
// LDS padded [128][40]: staging writes & frag reads ~2-way max (free, m136);
// b128 ops are structurally 8-deep regardless (1024B / 128B-per-clk).
// z selects Wq/Wk/Wv: z=0 (Q) scaled 0.125 -> [BH][N][64]; z=1 (K) ->
// [BH][N][64]; z=2 (V) written TRANSPOSED [BH][HD][N] (ushort4 stores).
// Layouts (HW-verified m89/m91/m120): A-frag (m=lane&15, k=quad*8+j),
// B-frag (k=quad*8+j, n=lane&15), C/D col=lane&15, row=quad*4+reg.
// ---------------------------------------------------------------------------
__global__ __launch_bounds__(256)
void gemm_qkv(const ushort* __restrict__ A,
              const ushort* __restrict__ W0, const ushort* __restrict__ W1,
              const ushort* __restrict__ W2,
              ushort* __restrict__ O0, ushort* __restrict__ O1,
              ushort* __restrict__ O2)
{
    const int z = blockIdx.z;
    const ushort* W = (z == 0) ? W0 : (z == 1) ? W1 : W2;

    __shared__ alignas(16) ushort As[128][40];
    __shared__ alignas(16) ushort Bs[128][40];

    const int t = threadIdx.x;
    const int lane = t & 63, w = t >> 6;
    const int quad = lane >> 4, l15 = lane & 15;
    const int wm = (w >> 1) * 64, wn = (w & 1) * 64;
    const int tileM = blockIdx.x * 128, tileN = blockIdx.y * 128;

    // staging: thread t covers uint4 chunks t and 256+t of each array.
    // chunk c: row = c>>2 (0..127), colgrp = (c&3)*8.
    const int r0 = t >> 2, r1 = 64 + (t >> 2);
    const int cg = (t & 3) * 8;
    const ushort* GA0 = A + (size_t)(tileM + r0) * D_ + cg;
    const ushort* GA1 = A + (size_t)(tileM + r1) * D_ + cg;
    const ushort* GB0 = W + (size_t)(tileN + r0) * D_ + cg;
    const ushort* GB1 = W + (size_t)(tileN + r1) * D_ + cg;

    f32x4 acc[4][4];
#pragma unroll
    for (int mt = 0; mt < 4; ++mt)
#pragma unroll
        for (int nt = 0; nt < 4; ++nt) acc[mt][nt] = (f32x4){0.f, 0.f, 0.f, 0.f};

    uint4 pa0 = *(const uint4*)GA0, pa1 = *(const uint4*)GA1;
    uint4 pb0 = *(const uint4*)GB0, pb1 = *(const uint4*)GB1;

    for (int k0 = 0; k0 < D_; k0 += 32) {
        __syncthreads();                 // prev tile's readers done
        *(uint4*)&As[r0][cg] = pa0;
        *(uint4*)&As[r1][cg] = pa1;
        *(uint4*)&Bs[r0][cg] = pb0;
        *(uint4*)&Bs[r1][cg] = pb1;
        __syncthreads();
        if (k0 + 32 < D_) {              // prefetch next tile (used next iter)
            pa0 = *(const uint4*)(GA0 + k0 + 32);
            pa1 = *(const uint4*)(GA1 + k0 + 32);
            pb0 = *(const uint4*)(GB0 + k0 + 32);
            pb1 = *(const uint4*)(GB1 + k0 + 32);
        }

        bf16x8 af[4], bf[4];
#pragma unroll
        for (int mt = 0; mt < 4; ++mt) af[mt] = *(const bf16x8*)&As[wm + mt * 16 + l15][quad * 8];
#pragma unroll
        for (int nt = 0; nt < 4; ++nt) bf[nt] = *(const bf16x8*)&Bs[wn + nt * 16 + l15][quad * 8];
#pragma unroll
        for (int mt = 0; mt < 4; ++mt)
#pragma unroll
            for (int nt = 0; nt < 4; ++nt)
                acc[mt][nt] = __builtin_amdgcn_mfma_f32_16x16x32_bf16(af[mt], bf[nt], acc[mt][nt], 0, 0, 0);
    }

    ushort* O = (z == 0) ? O0 : (z == 1) ? O1 : O2;
    const float scl = (z == 0) ? 0.125f : 1.0f;   // fold 1/sqrt(64) into Q
#pragma unroll
    for (int mt = 0; mt < 4; ++mt)
#pragma unroll
        for (int nt = 0; nt < 4; ++nt) {
            if (z == 2) {
                // V transposed: Vt[bh][dd][n], 4 consecutive n per 8B store
                int rg0 = tileM + wm + mt * 16 + quad * 4;
                int cgc = tileN + wn + nt * 16 + l15;
                int b = rg0 >> 11, n0 = rg0 & (N_ - 1);
                int h = cgc >> 6, dd = cgc & 63;
                ushort4 o4;
                o4.x = f2b(acc[mt][nt][0]); o4.y = f2b(acc[mt][nt][1]);
                o4.z = f2b(acc[mt][nt][2]); o4.w = f2b(acc[mt][nt][3]);
                *(ushort4*)&O[((size_t)((b * H_ + h) * HD_ + dd)) * N_ + n0] = o4;
            } else {
#pragma unroll
                for (int r = 0; r < 4; ++r) {
                    int rg = tileM + wm + mt * 16 + quad * 4 + r;
                    int cgc = tileN + wn + nt * 16 + l15;
                    int b = rg >> 11, n = rg & (N_ - 1);
                    int h = cgc >> 6, dd = cgc & 63;
                    O[(((size_t)(b * H_ + h)) * N_ + n) * HD_ + dd] = f2b(acc[mt][nt][r] * scl);
                }
            }
        }
}

// ---------------------------------------------------------------------------
// Final GEMM: out = AO @ Wo^T + bias, fp32 out [4096x1024].
// 128x64 tile (grid 32x16 = 512 blocks = 2/CU, vs 1/CU at 128x128 -> the
// 1-wave/SIMD latency cliff). 4 waves 2x2, each 64x32: af[4] x bf[2], 8 MFMA.
// Same register-prefetch staging as gemm_qkv.
// ---------------------------------------------------------------------------
__global__ __launch_bounds__(256)
void gemm_fin(const ushort* __restrict__ A, const ushort* __restrict__ W,
              const float* __restrict__ bias, float* __restrict__ Of)
{
    __shared__ alignas(16) ushort As[128][40];
    __shared__ alignas(16) ushort Bs[64][40];

    const int t = threadIdx.x;
    const int lane = t & 63, w = t >> 6;
    const int quad = lane >> 4, l15 = lane & 15;
    const int wm = (w >> 1) * 64, wn = (w & 1) * 32;
    const int tileM = blockIdx.x * 128, tileN = blockIdx.y * 64;

    const int r0 = t >> 2, r1 = 64 + (t >> 2);   // As rows; Bs uses r0 only
    const int cg = (t & 3) * 8;
    const ushort* GA0 = A + (size_t)(tileM + r0) * D_ + cg;
    const ushort* GA1 = A + (size_t)(tileM + r1) * D_ + cg;
    const ushort* GB0 = W + (size_t)(tileN + r0) * D_ + cg;

    f32x4 acc[4][2];
#pragma unroll
    for (int mt = 0; mt < 4; ++mt)
#pragma unroll
        for (int nt = 0; nt < 2; ++nt) acc[mt][nt] = (f32x4){0.f, 0.f, 0.f, 0.f};

    uint4 pa0 = *(const uint4*)GA0, pa1 = *(const uint4*)GA1;
    uint4 pb0 = *(const uint4*)GB0;

    for (int k0 = 0; k0 < D_; k0 += 32) {
        __syncthreads();
        *(uint4*)&As[r0][cg] = pa0;
        *(uint4*)&As[r1][cg] = pa1;
        *(uint4*)&Bs[r0 & 63][cg] = pb0;         // r0 < 64 always (t>>2)
        __syncthreads();
        if (k0 + 32 < D_) {
            pa0 = *(const uint4*)(GA0 + k0 + 32);
            pa1 = *(const uint4*)(GA1 + k0 + 32);
            pb0 = *(const uint4*)(GB0 + k0 + 32);
        }

        bf16x8 af[4], bf[2];
#pragma unroll
        for (int mt = 0; mt < 4; ++mt) af[mt] = *(const bf16x8*)&As[wm + mt * 16 + l15][quad * 8];
#pragma unroll
        for (int nt = 0; nt < 2; ++nt) bf[nt] = *(const bf16x8*)&Bs[wn + nt * 16 + l15][quad * 8];
#pragma unroll
        for (int mt = 0; mt < 4; ++mt)
#pragma unroll
            for (int nt = 0; nt < 2; ++nt)
                acc[mt][nt] = __builtin_amdgcn_mfma_f32_16x16x32_bf16(af[mt], bf[nt], acc[mt][nt], 0, 0, 0);
    }

#pragma unroll
    for (int mt = 0; mt < 4; ++mt)
#pragma unroll
        for (int nt = 0; nt < 2; ++nt)
#pragma unroll
            for (int r = 0; r < 4; ++r) {
                int rg = tileM + wm + mt * 16 + quad * 4 + r;
                int cgc = tileN + wn + nt * 16 + l15;
                Of[(size_t)rg * D_ + cgc] = acc[mt][nt][r] + bias[cgc];
            }
}

// ---------------------------------------------------------------------------
// MFMA adaptive-temperature causal flash attention (LDS-staged, reg-prefetch).
// 1D grid 1024 blocks, LPT order (qt descending), bh = bid&31 (XCD locality).
// 4 waves; wave w owns queries qt*64 + w*16 .. +15.
// Q/K bf16 [BH][N][64]; V pre-transposed [BH][64][N]; Q pre-scaled 1/8.
// Staging GLOBAL loads for kb+1 prefetch into VGPRs during kb's compute.
// Fixed shift C=8 (entropy/beta-softmax shift-invariant; |s|<~8).
// Pass 1: Z=sum e^(s-C), S=sum (s-C)e^(s-C) -> H=logZ-S/Z -> beta.
// Pass 2: w=e^(beta*(s-C)); O += w*V (P via wave-private LDS), Z'+=w; O/Z'.
// ---------------------------------------------------------------------------
__global__ __launch_bounds__(256)
void attn_mfma(const ushort* __restrict__ Q, const ushort* __restrict__ K,
               const ushort* __restrict__ VT, ushort* __restrict__ AO)
{
    const int bid = blockIdx.x;
    const int qt = 31 - (bid >> 5);
    const int bh = bid & 31;
    const size_t kvbase = (size_t)bh * N_ * HD_;

    __shared__ alignas(16) ushort Ks[64][72];       // [key][hd]
    __shared__ alignas(16) ushort Vt[64][72];       // [hd][key]
    __shared__ alignas(16) ushort Ps[4][4][296];    // wave-private P, grp-padded

    const int t = threadIdx.x;
    const int lane = t & 63, w = t >> 6;
    const int quad = lane >> 4, l15 = lane & 15;
    const float SH = 8.0f;

    // staging: thread t covers chunks (skey, skc) and (32+skey, skc)
    const int skey = t >> 3;            // 0..31
    const int skc  = (t & 7) * 8;       // 0..56
    const ushort* KS0 = K  + kvbase + (size_t)skey * HD_ + skc;        // + kb*64*HD_
    const ushort* KS1 = KS0 + 32 * HD_;
    const ushort* VS0 = VT + kvbase + (size_t)skey * N_ + skc;         // + kb*64
    const ushort* VS1 = VS0 + 32 * N_;

    // Q fragments (registers all kernel)
    bf16x8 aq0, aq1;
    {
        const size_t qr = kvbase + (size_t)(qt * 64 + w * 16 + l15) * HD_;
        aq0 = *(const bf16x8*)&Q[qr + quad * 8];
        aq1 = *(const bf16x8*)&Q[qr + 32 + quad * 8];
    }
    const int qrow = w * 16 + quad * 4;

    float ez[4] = {0.f, 0.f, 0.f, 0.f};
    float sz[4] = {0.f, 0.f, 0.f, 0.f};

    // ---------------- pass 1: Z, S ----------------
    uint4 pk0 = *(const uint4*)KS0;
    uint4 pk1 = *(const uint4*)KS1;
    for (int kb = 0; kb <= qt; ++kb) {
        __syncthreads();                       // prev tile's readers done
        *(uint4*)&Ks[skey][skc]      = pk0;    // vmcnt wait here, hidden by prev compute
        *(uint4*)&Ks[32 + skey][skc] = pk1;
        __syncthreads();
        if (kb < qt) {                         // prefetch kb+1 (consumed next iter)
            pk0 = *(const uint4*)(KS0 + (size_t)(kb + 1) * (64 * HD_));
            pk1 = *(const uint4*)(KS1 + (size_t)(kb + 1) * (64 * HD_));
        }
        if (kb < qt) {                         // off-diagonal: no masks
#pragma unroll
            for (int nt = 0; nt < 4; ++nt) {
                f32x4 sv = (f32x4){0.f, 0.f, 0.f, 0.f};
                sv = __builtin_amdgcn_mfma_f32_16x16x32_bf16(aq0, *(const bf16x8*)&Ks[nt * 16 + l15][quad * 8], sv, 0, 0, 0);
                sv = __builtin_amdgcn_mfma_f32_16x16x32_bf16(aq1, *(const bf16x8*)&Ks[nt * 16 + l15][32 + quad * 8], sv, 0, 0, 0);
#pragma unroll
                for (int r = 0; r < 4; ++r) {
                    float sh = sv[r] - SH;
                    float e = __expf(sh);
                    ez[r] += e;
                    sz[r] = fmaf(e, sh, sz[r]);
                }
            }
        } else {                               // diagonal: causal mask
#pragma unroll
            for (int nt = 0; nt < 4; ++nt) {
                f32x4 sv = (f32x4){0.f, 0.f, 0.f, 0.f};
                sv = __builtin_amdgcn_mfma_f32_16x16x32_bf16(aq0, *(const bf16x8*)&Ks[nt * 16 + l15][quad * 8], sv, 0, 0, 0);
                sv = __builtin_amdgcn_mfma_f32_16x16x32_bf16(aq1, *(const bf16x8*)&Ks[nt * 16 + l15][32 + quad * 8], sv, 0, 0, 0);
                const int kcol = nt * 16 + l15;
#pragma unroll
                for (int r = 0; r < 4; ++r) {
                    float sh = sv[r] - SH;
                    float e = (kcol <= qrow + r) ? __expf(sh) : 0.f;
                    ez[r] += e;
                    sz[r] = fmaf(e, sh, sz[r]);
                }
            }
        }
    }
    // hoisted 16-lane butterfly reduce
#pragma unroll
    for (int r = 0; r < 4; ++r) {
#pragma unroll
        for (int off = 1; off < 16; off <<= 1) {
            ez[r] += __shfl_xor(ez[r], off);
            sz[r] += __shfl_xor(sz[r], off);
        }
    }

    // ---------------- entropy -> beta ----------------
    float nbs[4], bl[4];   // w = exp(fma(beta, s, -beta*SH))
#pragma unroll
    for (int r = 0; r < 4; ++r) {
        float Z = ez[r];
        float Hh = __logf(Z) - sz[r] / Z;
        float bb = 1.f;
        if (Hh > 0.5f) {
            float e2 = Hh * Hh;
            float p = -0.037f * e2 * e2 + 0.481f * e2 * Hh - 2.3f * e2 + 4.917f * Hh - 1.791f;
            bb = fmaxf(p, 1.f);
        }
        bl[r] = bb;
        nbs[r] = -bb * SH;
    }

    // ---------------- pass 2: O, Z' ----------------
    f32x4 ov[4];
#pragma unroll
    for (int nt = 0; nt < 4; ++nt) ov[nt] = (f32x4){0.f, 0.f, 0.f, 0.f};
    float zp[4] = {0.f, 0.f, 0.f, 0.f};

    pk0 = *(const uint4*)KS0;
    pk1 = *(const uint4*)KS1;
    uint4 pv0 = *(const uint4*)VS0;
    uint4 pv1 = *(const uint4*)VS1;
    for (int kb = 0; kb <= qt; ++kb) {
        __syncthreads();
        *(uint4*)&Ks[skey][skc]      = pk0;
        *(uint4*)&Ks[32 + skey][skc] = pk1;
        *(uint4*)&Vt[skey][skc]      = pv0;
        *(uint4*)&Vt[32 + skey][skc] = pv1;
        __syncthreads();
        if (kb < qt) {
            pk0 = *(const uint4*)(KS0 + (size_t)(kb + 1) * (64 * HD_));
            pk1 = *(const uint4*)(KS1 + (size_t)(kb + 1) * (64 * HD_));
            pv0 = *(const uint4*)(VS0 + (kb + 1) * 64);
            pv1 = *(const uint4*)(VS1 + (kb + 1) * 64);
        }
        const bool diag = (kb == qt);

        float wv[4][4];
#pragma unroll
        for (int nt = 0; nt < 4; ++nt) {
            f32x4 sv = (f32x4){0.f, 0.f, 0.f, 0.f};
            sv = __builtin_amdgcn_mfma_f32_16x16x32_bf16(aq0, *(const bf16x8*)&Ks[nt * 16 + l15][quad * 8], sv, 0, 0, 0);
            sv = __builtin_amdgcn_mfma_f32_16x16x32_bf16(aq1, *(const bf16x8*)&Ks[nt * 16 + l15][32 + quad * 8], sv, 0, 0, 0);
            const int kcol = nt * 16 + l15;
#pragma unroll
            for (int r = 0; r < 4; ++r) {
                float e = __expf(fmaf(bl[r], sv[r], nbs[r]));
                wv[nt][r] = (!diag || (kcol <= qrow + r)) ? e : 0.f;
            }
        }
        // P -> wave-private LDS (C-layout write, A-layout read; same-wave DS in-order)
#pragma unroll
        for (int nt = 0; nt < 4; ++nt)
#pragma unroll
            for (int r = 0; r < 4; ++r)
                Ps[w][quad][r * 72 + nt * 16 + l15] = f2b_fast(wv[nt][r]);
#pragma unroll
        for (int r = 0; r < 4; ++r)
            zp[r] += (wv[0][r] + wv[1][r]) + (wv[2][r] + wv[3][r]);

        bf16x8 pa0 = *(const bf16x8*)&Ps[w][l15 >> 2][(l15 & 3) * 72 + quad * 8];
        bf16x8 pa1 = *(const bf16x8*)&Ps[w][l15 >> 2][(l15 & 3) * 72 + 32 + quad * 8];
#pragma unroll
        for (int nt = 0; nt < 4; ++nt) {
            ov[nt] = __builtin_amdgcn_mfma_f32_16x16x32_bf16(pa0, *(const bf16x8*)&Vt[nt * 16 + l15][quad * 8], ov[nt], 0, 0, 0);
            ov[nt] = __builtin_amdgcn_mfma_f32_16x16x32_bf16(pa1, *(const bf16x8*)&Vt[nt * 16 + l15][32 + quad * 8], ov[nt], 0, 0, 0);
        }
    }
    // hoisted Z' butterfly
#pragma unroll
    for (int r = 0; r < 4; ++r)
#pragma unroll
        for (int off = 1; off < 16; off <<= 1) zp[r] += __shfl_xor(zp[r], off);

    // ---------------- write AO [B, N, D] bf16 ----------------
    const int b = bh >> 4, h = bh & 15;
#pragma unroll
    for (int r = 0; r < 4; ++r) {
        int qg = qt * 64 + w * 16 + quad * 4 + r;
        float inv = 1.f / zp[r];
        size_t rowoff = ((size_t)(b * N_ + qg)) * D_ + h * HD_;
#pragma unroll
        for (int nt = 0; nt < 4; ++nt)
            AO[rowoff + nt * 16 + l15] = f2b(ov[nt][r] * inv);
    }
}

// ---------------------------------------------------------------------------
extern "C" void kernel_launch(void* const* d_in, const int* in_sizes, int n_in,
                              void* d_out, int out_size, void* d_ws, size_t ws_size,
                              hipStream_t stream)
{
    const float* x  = (const float*)d_in[0];
    const float* Wq = (const float*)d_in[1];
    const float* Wk = (const float*)d_in[2];
    const float* Wv = (const float*)d_in[3];
    const float* Wo = (const float*)d_in[4];
    const float* bo = (const float*)d_in[5];
    float* out = (float*)d_out;

    ushort* ws  = (ushort*)d_ws;
    ushort* xb  = ws;                       // 4096*1024
    ushort* wqb = ws + 4194304;
    ushort* wkb = ws + 5242880;
    ushort* wvb = ws + 6291456;
    ushort* wob = ws + 7340032;
    ushort* Qb  = ws + 8388608;             // [32][2048][64]
    ushort* Kb  = ws + 12582912;            // [32][2048][64]
    ushort* Vtb = ws + 16777216;            // [32][64][2048]  (transposed V)
    ushort* aob = ws + 20971520;            // 4096*1024

    cvt_all<<<8192, 256, 0, stream>>>(x, Wq, Wk, Wv, Wo, xb);

    gemm_qkv<<<dim3(32, 8, 3), 256, 0, stream>>>(
        xb, wqb, wkb, wvb, Qb, Kb, Vtb);

    attn_mfma<<<dim3(1024), 256, 0, stream>>>(Qb, Kb, Vtb, aob);

    gemm_fin<<<dim3(32, 16), 256, 0, stream>>>(aob, wob, bo, out);
}